// Round 7
// baseline (522.326 us; speedup 1.0000x reference)
//
#include <hip/hip_runtime.h>
#include <cstdint>
#include <cstddef>

// NTM cell: B=512, INP=512, C=1024, N=256, D=128, H=8
// d_out (floats): h1n(524288) c1n(524288) h2n(524288) c2n(524288)
//                 w_r(1048576) r(524288) M(16777216)

typedef __attribute__((ext_vector_type(4))) float f32x4;
typedef __attribute__((ext_vector_type(8))) __bf16 bf16x8;
typedef __attribute__((ext_vector_type(4))) unsigned short u16x4;
typedef __attribute__((ext_vector_type(8))) unsigned short u16x8;

struct ASeg { const unsigned short* A; int ldA; int kt; };
struct WSeg { const float* W; int ldW; };

__device__ __forceinline__ unsigned short f2bf(float f) {
  return __builtin_bit_cast(unsigned short, (__bf16)f);   // HW RNE convert
}
__device__ __forceinline__ float sigmoidf_(float x) { return 1.f / (1.f + expf(-x)); }
__device__ __forceinline__ float softplusf_(float x) {
  return fmaxf(x, 0.f) + log1pf(expf(-fabsf(x)));         // stable logaddexp(x,0)
}

// 256-block grids: chunked XCD remap (bijection; perf-only). 4 M-tiles sharing a
// B-panel land on one XCD so the weight panel is read from HBM once per XCD.
__device__ __forceinline__ void xcd_decode(int& k, int& g) {
  int hid = blockIdx.x;                // 0..255
  int xcd = hid & 7, slot = hid >> 3;  // 32 slots per xcd
  g = xcd + 8 * (slot >> 2);           // 64 B-panel groups
  k = slot & 3;                        // 4 M-tiles per group
}

// ================= GEMM core: 128x64 tile, BK=64, 256 thr (4 waves of 32x64) =====
// A: bf16 in global (pre-converted), staged via global_load_lds (16B) with
// inverse-swizzled SOURCE columns (linear LDS dest, m173 pattern).
// B: fp32 weight rows, converted inline, swizzled ds_write.
// LDS layout: row r, logical elem e at phys r*64 + (e ^ ((r&7)<<3)).

__device__ __forceinline__ void stage_tile(
    unsigned short* lAb, unsigned short* lBb,
    const float* (*s_brow)[64],
    const unsigned short* A0, int ldA0, const unsigned short* A1, int ldA1,
    const unsigned short* A2, int ldA2, int b0, int b1, int kt, int t)
{
  int si; const unsigned short* A; int ldA; int ktl;
  if (kt < b0)      { si = 0; ktl = kt;      A = A0; ldA = ldA0; }
  else if (kt < b1) { si = 1; ktl = kt - b0; A = A1; ldA = ldA1; }
  else              { si = 2; ktl = kt - b1; A = A2; ldA = ldA2; }
  const int kl = ktl * 64;
  const int wave = t >> 6, lane = t & 63;
  // ---- A: 4 issues/wave; 64 lanes x 16B = 8 rows x 64 bf16, linear LDS dest ----
  const int a_r8 = lane >> 3;                          // row within 8-row group
  const int a_col = (((lane & 7) ^ a_r8) * 8);         // inverse-swizzled src col
#pragma unroll
  for (int q = 0; q < 4; ++q) {
    const int R = (wave * 4 + q) * 8;
    const unsigned short* src = A + (size_t)(R + a_r8) * ldA + kl + a_col;
    __builtin_amdgcn_global_load_lds(
        (const __attribute__((address_space(1))) void*)src,
        (__attribute__((address_space(3))) void*)(lAb + R * 64), 16, 0, 0);
  }
  // ---- B: 64 rows fp32 -> bf16, swizzled ds_write ----
  const int brow0 = t >> 4, bseg = t & 15;
#pragma unroll
  for (int i = 0; i < 4; ++i) {
    const int row = brow0 + 16 * i;
    const float* wp = s_brow[si][row];
    f32x4 v = *(const f32x4*)(wp + kl + bseg * 4);
    u16x4 p; p.x = f2bf(v.x); p.y = f2bf(v.y); p.z = f2bf(v.z); p.w = f2bf(v.w);
    *(u16x4*)&lBb[row * 64 + ((bseg * 4) ^ ((row & 7) << 3))] = p;
  }
}

__device__ __forceinline__ void mfma_tile(const unsigned short* lAb,
                                          const unsigned short* lBb,
                                          int t, f32x4 (&acc)[2][4])
{
  const int wave = t >> 6, lane = t & 63;
  const int lr = lane & 15, lk = lane >> 4;
#pragma unroll
  for (int kk = 0; kk < 2; ++kk) {
    bf16x8 af[2], bfr[4];
#pragma unroll
    for (int mi = 0; mi < 2; ++mi) {
      const int ar = wave * 32 + mi * 16 + lr;
      af[mi] = *(const bf16x8*)&lAb[ar * 64 + ((kk * 32 + lk * 8) ^ ((ar & 7) << 3))];
    }
#pragma unroll
    for (int ni = 0; ni < 4; ++ni) {
      const int br = ni * 16 + lr;
      bfr[ni] = *(const bf16x8*)&lBb[br * 64 + ((kk * 32 + lk * 8) ^ ((br & 7) << 3))];
    }
#pragma unroll
    for (int mi = 0; mi < 2; ++mi)
#pragma unroll
      for (int ni = 0; ni < 4; ++ni)
        acc[mi][ni] = __builtin_amdgcn_mfma_f32_16x16x32_bf16(af[mi], bfr[ni], acc[mi][ni], 0, 0, 0);
  }
}

// 2-phase pipeline: stage(next) -> mfma(cur) -> one barrier per K-step.
// Barrier drains vmcnt+lgkmcnt => buffer kt+1 complete before its mfma;
// mfma(cur) reads drained before its buffer is overwritten. Race-free.
#define GEMM_PIPELINE(A0, LD0, A1, LD1, A2, LD2, B0, B1, TOTAL)                    \
  stage_tile(lA[0], lB[0], s_brow, A0, LD0, A1, LD1, A2, LD2, B0, B1, 0, t);       \
  __syncthreads();                                                                 \
  _Pragma("unroll 1")                                                              \
  for (int kt = 0; kt < (TOTAL); ++kt) {                                           \
    const int cur = kt & 1;                                                        \
    if (kt + 1 < (TOTAL))                                                          \
      stage_tile(lA[cur ^ 1], lB[cur ^ 1], s_brow, A0, LD0, A1, LD1, A2, LD2,      \
                 B0, B1, kt + 1, t);                                               \
    mfma_tile(lA[cur], lB[cur], t, acc);                                           \
    __syncthreads();                                                               \
  }

// ---------------- fused LSTM GEMM + cell update (gate order i,f,g,o) ----------
// Gate-interleaved cols: tile col c -> W row (c>>4)*1024 + j0 + (c&15); each
// thread's 4 ni-fragments are the 4 gates of hidden unit j0+(lane&15).
__global__ __launch_bounds__(256) void lstm_gemm(
    ASeg a0, ASeg a1, ASeg a2, WSeg w0, WSeg w1, WSeg w2,
    const float* __restrict__ bih, const float* __restrict__ bhh,
    const float* __restrict__ cprev,
    float* __restrict__ hout, float* __restrict__ cout,
    unsigned short* __restrict__ hb)
{
  __shared__ __align__(16) unsigned short lA[2][128 * 64];
  __shared__ __align__(16) unsigned short lB[2][64 * 64];
  __shared__ const float* s_brow[3][64];
  const int t = threadIdx.x;
  int k, g; xcd_decode(k, g);
  const int m0 = k * 128, j0 = g * 16;

  if (t < 192) {
    const int si = t >> 6, row = t & 63;
    const float* W = si == 0 ? w0.W : si == 1 ? w1.W : w2.W;
    const int ldW  = si == 0 ? w0.ldW : si == 1 ? w1.ldW : w2.ldW;
    if (W) s_brow[si][row] = W + (size_t)((row >> 4) * 1024 + j0 + (row & 15)) * ldW;
  }
  __syncthreads();

  f32x4 acc[2][4];
#pragma unroll
  for (int i = 0; i < 2; ++i)
#pragma unroll
    for (int j = 0; j < 4; ++j) acc[i][j] = (f32x4){0.f, 0.f, 0.f, 0.f};

  const unsigned short* A0 = a0.A + (size_t)m0 * a0.ldA;
  const unsigned short* A1 = a1.A + (size_t)m0 * a1.ldA;
  const unsigned short* A2 = a2.A ? a2.A + (size_t)m0 * a2.ldA : a0.A;
  const int b0 = a0.kt, b1 = b0 + a1.kt, total = b1 + a2.kt;
  GEMM_PIPELINE(A0, a0.ldA, A1, a1.ldA, A2, a2.ldA, b0, b1, total)

  // epilogue: C layout col=lane&15, row=(lane>>4)*4+reg (m89-verified)
  const int lane = t & 63, wave = t >> 6;
  const int lr = lane & 15, lk = lane >> 4;
  const int j = j0 + lr;
  float bs0 = bih[j] + bhh[j];
  float bs1 = bih[1024 + j] + bhh[1024 + j];
  float bs2 = bih[2048 + j] + bhh[2048 + j];
  float bs3 = bih[3072 + j] + bhh[3072 + j];
#pragma unroll
  for (int mi = 0; mi < 2; ++mi) {
#pragma unroll
    for (int jp = 0; jp < 4; ++jp) {
      const int r = m0 + wave * 32 + mi * 16 + lk * 4 + jp;
      float gi = acc[mi][0][jp] + bs0;
      float gf = acc[mi][1][jp] + bs1;
      float gc = acc[mi][2][jp] + bs2;
      float go = acc[mi][3][jp] + bs3;
      float cp = cprev[(size_t)r * 1024 + j];
      float cn = sigmoidf_(gf) * cp + sigmoidf_(gi) * tanhf(gc);
      float hn = sigmoidf_(go) * tanhf(cn);
      cout[(size_t)r * 1024 + j] = cn;
      hout[(size_t)r * 1024 + j] = hn;
      hb[(size_t)r * 1024 + j] = f2bf(hn);
    }
  }
}

// ---------------- head projections: RK, WK, ER(sig), AD(tanh) + small heads ----
__global__ __launch_bounds__(256) void heads_gemm(
    const unsigned short* __restrict__ A,
    const float* W0, const float* W1, const float* W2, const float* W3,
    const float* bb0, const float* bb1, const float* bb2, const float* bb3,
    const float* W_rb, const float* b_rb, const float* W_wb, const float* b_wb,
    const float* W_sh, const float* b_sh, const float* W_ga, const float* b_ga,
    float* o0, float* o1, float* o2, float* o3,
    float* Brw, float* Bww, float* SHw, float* GAw)
{
  __shared__ __align__(16) unsigned short lA[2][128 * 64];
  __shared__ __align__(16) unsigned short lB[2][64 * 64];
  __shared__ const float* s_brow[3][64];
  const int t = threadIdx.x;
  const bool small = (blockIdx.x >= 256);
  int m0, n0 = 0, z = 4;
  if (!small) {
    int k, g; xcd_decode(k, g);
    m0 = k * 128; n0 = (g & 15) * 64; z = g >> 4;
  } else {
    m0 = (blockIdx.x - 256) * 128;
  }
  const float* W  = z == 0 ? W0 : z == 1 ? W1 : z == 2 ? W2 : z == 3 ? W3 : nullptr;
  const float* bb = z == 0 ? bb0 : z == 1 ? bb1 : z == 2 ? bb2 : bb3;
  float* o        = z == 0 ? o0 : z == 1 ? o1 : z == 2 ? o2 : o3;

  if (t < 64) {
    if (!small) {
      s_brow[0][t] = W + (size_t)(n0 + t) * 1024;
    } else {
      const float* p;
      if (t < 8)       p = W_rb + (size_t)t * 1024;
      else if (t < 16) p = W_wb + (size_t)(t - 8) * 1024;
      else if (t < 40) p = W_sh + (size_t)(t - 16) * 1024;
      else if (t < 48) p = W_ga + (size_t)(t - 40) * 1024;
      else             p = W_ga;            // dummy rows 48..63, outputs skipped
      s_brow[0][t] = p;
    }
  }
  __syncthreads();

  f32x4 acc[2][4];
#pragma unroll
  for (int i = 0; i < 2; ++i)
#pragma unroll
    for (int j = 0; j < 4; ++j) acc[i][j] = (f32x4){0.f, 0.f, 0.f, 0.f};

  const unsigned short* A0 = A + (size_t)m0 * 1024;
  GEMM_PIPELINE(A0, 1024, A0, 1024, A0, 1024, 16, 16, 16)

  const int lane = t & 63, wave = t >> 6;
  const int lr = lane & 15, lk = lane >> 4;
  if (!small) {
#pragma unroll
    for (int mi = 0; mi < 2; ++mi) {
#pragma unroll
      for (int ni = 0; ni < 4; ++ni) {
        const int col = n0 + ni * 16 + lr;
        const float bv = bb[col];
#pragma unroll
        for (int jp = 0; jp < 4; ++jp) {
          const int r = m0 + wave * 32 + mi * 16 + lk * 4 + jp;
          float v = acc[mi][ni][jp] + bv;
          if (z == 2) v = sigmoidf_(v);
          else if (z == 3) v = tanhf(v);
          o[(size_t)r * 1024 + col] = v;
        }
      }
    }
  } else {
#pragma unroll
    for (int mi = 0; mi < 2; ++mi) {
#pragma unroll
      for (int ni = 0; ni < 4; ++ni) {
        const int c = ni * 16 + lr;
#pragma unroll
        for (int jp = 0; jp < 4; ++jp) {
          const int r = m0 + wave * 32 + mi * 16 + lk * 4 + jp;
          const float v = acc[mi][ni][jp];
          if (c < 8)       Brw[r * 8 + c] = softplusf_(v + b_rb[c]);
          else if (c < 16) Bww[r * 8 + (c - 8)] = softplusf_(v + b_wb[c - 8]);
          else if (c < 40) SHw[(size_t)r * 24 + (c - 16)] = v + b_sh[c - 16];
          else if (c < 48) GAw[r * 8 + (c - 40)] = v + b_ga[c - 40];
        }
      }
    }
  }
}

// ---------------- fp32 -> bf16 convert for GEMM A operands ----------------
// dst chunks(x8): xb 0..32767 | rb ..98303 | h1b ..163839 | h2b ..229375
__global__ __launch_bounds__(256) void cvt_bf16(
    const float* __restrict__ x, const float* __restrict__ rp,
    const float* __restrict__ h1, const float* __restrict__ h2,
    unsigned short* __restrict__ ob)
{
  const int i = blockIdx.x * 256 + threadIdx.x;       // 896 blocks
  const float* src; int off;
  if (i < 32768)       { src = x;  off = i; }
  else if (i < 98304)  { src = rp; off = i - 32768; }
  else if (i < 163840) { src = h1; off = i - 98304; }
  else                 { src = h2; off = i - 163840; }
  f32x4 a = *(const f32x4*)(src + (size_t)off * 8);
  f32x4 c = *(const f32x4*)(src + (size_t)off * 8 + 4);
  u16x8 p;
  p[0] = f2bf(a.x); p[1] = f2bf(a.y); p[2] = f2bf(a.z); p[3] = f2bf(a.w);
  p[4] = f2bf(c.x); p[5] = f2bf(c.y); p[6] = f2bf(c.z); p[7] = f2bf(c.w);
  *(u16x8*)(ob + (size_t)i * 8) = p;
}

// ---------------- fused memory write + read ----------------
// cosine logits: s_w[h][n] = (M[n]·K[h]) / max(|M[n]|,eps) * scale[h], scale=beta/|K|
// Keys preloaded to registers (32 f32x4) — j-loop does zero LDS reads.
__device__ __forceinline__ void cos_pass(const float* __restrict__ Mbase,
                                         const float (*s_k)[128],
                                         const float* s_scale, float (*s_w)[256],
                                         int b, int t)
{
  const int l8 = t & 7, rg = t >> 3;
  f32x4 kv0[8], kv1[8], kv2[8], kv3[8];
#pragma unroll
  for (int h = 0; h < 8; ++h) {
    kv0[h] = *(const f32x4*)&s_k[h][(l8 + 0) * 4];
    kv1[h] = *(const f32x4*)&s_k[h][(l8 + 8) * 4];
    kv2[h] = *(const f32x4*)&s_k[h][(l8 + 16) * 4];
    kv3[h] = *(const f32x4*)&s_k[h][(l8 + 24) * 4];
  }
#pragma unroll 1
  for (int j = 0; j < 8; ++j) {
    const int n = j * 32 + rg;
    const float* mr = Mbase + ((size_t)b * 256 + n) * 128;
    f32x4 v0 = *(const f32x4*)(mr + (l8 + 0) * 4);
    f32x4 v1 = *(const f32x4*)(mr + (l8 + 8) * 4);
    f32x4 v2 = *(const f32x4*)(mr + (l8 + 16) * 4);
    f32x4 v3 = *(const f32x4*)(mr + (l8 + 24) * 4);
    f32x4 sv = v0 * v0 + v1 * v1 + v2 * v2 + v3 * v3;
    float sq = sv.x + sv.y + sv.z + sv.w;
    float dot[8];
#pragma unroll
    for (int h = 0; h < 8; ++h) {
      f32x4 dv = v0 * kv0[h] + v1 * kv1[h] + v2 * kv2[h] + v3 * kv3[h];
      dot[h] = dv.x + dv.y + dv.z + dv.w;
    }
#pragma unroll
    for (int mk = 1; mk < 8; mk <<= 1) {
      sq += __shfl_xor(sq, mk, 64);
#pragma unroll
      for (int h = 0; h < 8; ++h) dot[h] += __shfl_xor(dot[h], mk, 64);
    }
    if (l8 == 0) {
      const float invM = 1.f / fmaxf(sqrtf(sq), 1e-12f);
#pragma unroll
      for (int h = 0; h < 8; ++h) s_w[h][n] = dot[h] * invM * s_scale[h];
    }
  }
}

__device__ __forceinline__ void softmax256(float (*s_w)[256], int t) {
  const int h = t >> 5, l32 = t & 31;
  float v[8]; float mx = -3.4e38f;
#pragma unroll
  for (int i = 0; i < 8; ++i) { v[i] = s_w[h][l32 + 32 * i]; mx = fmaxf(mx, v[i]); }
#pragma unroll
  for (int mk = 1; mk < 32; mk <<= 1) mx = fmaxf(mx, __shfl_xor(mx, mk, 64));
  float sum = 0.f;
#pragma unroll
  for (int i = 0; i < 8; ++i) { v[i] = expf(v[i] - mx); sum += v[i]; }
#pragma unroll
  for (int mk = 1; mk < 32; mk <<= 1) sum += __shfl_xor(sum, mk, 64);
  const float inv = 1.f / sum;
#pragma unroll
  for (int i = 0; i < 8; ++i) s_w[h][l32 + 32 * i] = v[i] * inv;
}

__global__ __launch_bounds__(256, 2) void ntm_rw(
    const float* __restrict__ Mp, const float* __restrict__ WK,
    const float* __restrict__ ER, const float* __restrict__ AD,
    const float* __restrict__ RK,
    const float* __restrict__ Bw, const float* __restrict__ Br,
    const float* __restrict__ SH, const float* __restrict__ GA,
    float* __restrict__ Mo, float* __restrict__ wr_o, float* __restrict__ r_o)
{
  const int b = blockIdx.x, t = threadIdx.x;
  __shared__ __align__(16) float s_wk[8][128], s_er[8][128], s_ad[8][128], s_rk[8][128];
  __shared__ __align__(16) float s_w[8][256], s_w2[8][256];
  __shared__ __align__(16) float s_part[8][8][128];
  __shared__ float s_scw[8], s_scr[8], s_sh3[8][3], s_g[8];

  {
    const int h = t >> 5, d16 = (t & 31) * 4;
    const size_t off = (size_t)b * 1024 + t * 4;
    *(f32x4*)&s_wk[h][d16] = *(const f32x4*)(WK + off);
    *(f32x4*)&s_er[h][d16] = *(const f32x4*)(ER + off);
    *(f32x4*)&s_ad[h][d16] = *(const f32x4*)(AD + off);
    *(f32x4*)&s_rk[h][d16] = *(const f32x4*)(RK + off);
  }
  __syncthreads();
  if (t < 64) {                                  // key norms, wave-parallel
    const int h = t >> 3, l8 = t & 7;
    f32x4 aw = {0,0,0,0}, ar = {0,0,0,0};
#pragma unroll
    for (int q = 0; q < 4; ++q) {
      f32x4 w = *(const f32x4*)&s_wk[h][(l8 + q * 8) * 4];
      f32x4 r = *(const f32x4*)&s_rk[h][(l8 + q * 8) * 4];
      aw += w * w; ar += r * r;
    }
    float sw = aw.x + aw.y + aw.z + aw.w;
    float sr = ar.x + ar.y + ar.z + ar.w;
#pragma unroll
    for (int mk = 1; mk < 8; mk <<= 1) {
      sw += __shfl_xor(sw, mk, 64); sr += __shfl_xor(sr, mk, 64);
    }
    if (l8 == 0) {
      s_scw[h] = Bw[b * 8 + h] / fmaxf(sqrtf(sw), 1e-12f);
      s_scr[h] = Br[b * 8 + h] / fmaxf(sqrtf(sr), 1e-12f);
    }
  }
  if (t < 8) {
    s_g[t] = 1.f + softplusf_(GA[b * 8 + t]);
    float s0 = SH[b * 24 + t * 3], s1 = SH[b * 24 + t * 3 + 1], s2 = SH[b * 24 + t * 3 + 2];
    float mx = fmaxf(s0, fmaxf(s1, s2));
    float e0 = expf(s0 - mx), e1 = expf(s1 - mx), e2 = expf(s2 - mx);
    float inv = 1.f / (e0 + e1 + e2);
    s_sh3[t][0] = e0 * inv; s_sh3[t][1] = e1 * inv; s_sh3[t][2] = e2 * inv;
  }
  __syncthreads();

  // -------- write head: content weights on M_prev --------
  cos_pass(Mp, s_wk, s_scw, s_w, b, t);
  __syncthreads();
  softmax256(s_w, t);                    // s_w = w_w
  __syncthreads();

  // -------- M = Mp*(1 - sum_h w e) + sum_h w a  (erase/add preloaded) --------
  {
    const int d16 = (t & 31) * 4;
    f32x4 er8[8], ad8[8];
#pragma unroll
    for (int h = 0; h < 8; ++h) {
      er8[h] = *(const f32x4*)&s_er[h][d16];
      ad8[h] = *(const f32x4*)&s_ad[h][d16];
    }
#pragma unroll 1
    for (int j = 0; j < 32; ++j) {
      const int idx = j * 256 + t;       // all 8192 float4 chunks of M[b]
      const int n = idx >> 5;
      f32x4 m = *(const f32x4*)(Mp + (size_t)b * 32768 + (size_t)idx * 4);
      f32x4 er = {0,0,0,0}, ad = {0,0,0,0};
#pragma unroll
      for (int h = 0; h < 8; ++h) {
        const float w = s_w[h][n];
        er += w * er8[h];
        ad += w * ad8[h];
      }
      f32x4 o;
#pragma unroll
      for (int e = 0; e < 4; ++e) o[e] = m[e] * (1.f - er[e]) + ad[e];
      *(f32x4*)(Mo + (size_t)b * 32768 + (size_t)idx * 4) = o;
    }
  }
  __syncthreads();                       // Mo visible block-wide

  // -------- read head: content on new M (L1/L2-hot) --------
  cos_pass(Mo, s_rk, s_scr, s_w, b, t);
  __syncthreads();
  softmax256(s_w, t);                    // s_w = w_c
  __syncthreads();

  // -------- shift + sharpen --------
  {
    const int h = t >> 5, l32 = t & 31;
    float vals[8]; float sum = 0.f;
#pragma unroll
    for (int i = 0; i < 8; ++i) {
      const int n = l32 + 32 * i;
      float ws = s_w[h][(n + 1) & 255] * s_sh3[h][0]
               + s_w[h][n] * s_sh3[h][1]
               + s_w[h][(n - 1) & 255] * s_sh3[h][2];
      float wg = powf(ws, s_g[h]);
      vals[i] = wg; sum += wg;
    }
#pragma unroll
    for (int mk = 1; mk < 32; mk <<= 1) sum += __shfl_xor(sum, mk, 64);
    const float inv = 1.f / (sum + 1e-12f);
#pragma unroll
    for (int i = 0; i < 8; ++i) {
      const int n = l32 + 32 * i;
      const float w = vals[i] * inv;
      s_w2[h][n] = w;
      wr_o[((size_t)b * 8 + h) * 256 + n] = w;
    }
  }
  __syncthreads();

  // -------- r = w_r @ M : n-parallel partials, then LDS reduce --------
  {
    const int gq = t >> 5;               // n-residue group
    const int q = t & 31;                // d-chunk
    f32x4 pr[8];
#pragma unroll
    for (int h = 0; h < 8; ++h) pr[h] = (f32x4){0,0,0,0};
#pragma unroll 1
    for (int j = 0; j < 32; ++j) {
      const int n = j * 8 + gq;
      f32x4 v = *(const f32x4*)(Mo + (size_t)b * 32768 + (size_t)n * 128 + q * 4);
#pragma unroll
      for (int h = 0; h < 8; ++h) pr[h] += s_w2[h][n] * v;
    }
#pragma unroll
    for (int h = 0; h < 8; ++h) *(f32x4*)&s_part[gq][h][q * 4] = pr[h];
  }
  __syncthreads();
  {
    const int h = t >> 5, q = t & 31;
    f32x4 a = (f32x4){0,0,0,0};
#pragma unroll
    for (int g2 = 0; g2 < 8; ++g2) a += *(const f32x4*)&s_part[g2][h][q * 4];
    *(f32x4*)(r_o + ((size_t)b * 8 + h) * 128 + q * 4) = a;
  }
}

// ---------------- launch ----------------
extern "C" void kernel_launch(void* const* d_in, const int* in_sizes, int n_in,
                              void* d_out, int out_size, void* d_ws, size_t ws_size,
                              hipStream_t stream)
{
  const float* x      = (const float*)d_in[0];
  const float* h1     = (const float*)d_in[1];
  const float* c1     = (const float*)d_in[2];
  const float* h2     = (const float*)d_in[3];
  const float* c2     = (const float*)d_in[4];
  const float* r_prev = (const float*)d_in[6];
  const float* M_prev = (const float*)d_in[7];
  const float* W_ih1  = (const float*)d_in[8];
  const float* W_hh1  = (const float*)d_in[9];
  const float* b_ih1  = (const float*)d_in[10];
  const float* b_hh1  = (const float*)d_in[11];
  const float* W_ih2  = (const float*)d_in[12];
  const float* W_hh2  = (const float*)d_in[13];
  const float* b_ih2  = (const float*)d_in[14];
  const float* b_hh2  = (const float*)d_in[15];
  const float* W_rk   = (const float*)d_in[16];
  const float* b_rk   = (const float*)d_in[17];
  const float* W_wk   = (const float*)d_in[18];
  const float* b_wk   = (const float*)d_in[19];
  const float* W_rb   = (const float*)d_in[20];
  const float* b_rb   = (const float*)d_in[21];
  const float* W_wb   = (const float*)d_in[22];
  const float* b_wb   = (const float*)d_in[23];
  const float* W_er   = (const float*)d_in[24];
  const float* b_er   = (const float*)d_in[25];
  const float* W_ad   = (const float*)d_in[26];
  const float* b_ad   = (const float*)d_in[27];
  const float* W_sh   = (const float*)d_in[28];
  const float* b_sh   = (const float*)d_in[29];
  const float* W_ga   = (const float*)d_in[30];
  const float* b_ga   = (const float*)d_in[31];

  float* out = (float*)d_out;
  float* h1n = out;
  float* c1n = out + 524288;
  float* h2n = out + 1048576;
  float* c2n = out + 1572864;
  float* wro = out + 2097152;
  float* r_o = out + 3145728;
  float* M_o = out + 3670016;

  // ws layout: fp32 head buffers (8.49 MB) then bf16 A buffers (5.77 MB).
  // bf16 buffers are dead before ntm_rw runs -> may fall back to M_o tail.
  float* wsf = (float*)d_ws;
  float* RK  = wsf;                     // 524288
  float* WKb = RK + 524288;
  float* ER  = WKb + 524288;
  float* AD  = ER + 524288;
  float* Brb = AD + 524288;             // 4096
  float* Bwb = Brb + 4096;
  float* SHb = Bwb + 4096;              // 12288
  float* GAb = SHb + 12288;             // 4096
  const size_t f32_need  = 2121728;     // floats
  const size_t bf16_need = 2883584;     // shorts
  unsigned short* bfb;
  if (ws_size >= f32_need * 4 + bf16_need * 2) {
    bfb = (unsigned short*)(wsf + f32_need);
  } else {
    bfb = (unsigned short*)(M_o + (16777216 - (bf16_need + 1) / 2));
  }
  unsigned short* xb   = bfb;           // 262144
  unsigned short* rb   = xb + 262144;   // 524288 each
  unsigned short* h1b  = rb + 524288;
  unsigned short* h2b  = h1b + 524288;
  unsigned short* h1nb = h2b + 524288;
  unsigned short* h2nb = h1nb + 524288;

  // 1) convert external fp32 GEMM-A operands to bf16 (xb|rb|h1b|h2b)
  cvt_bf16<<<896, 256, 0, stream>>>(x, r_prev, h1, h2, xb);

  // 2) LSTM1: gates = [x | r_prev] @ W_ih1^T + h1 @ W_hh1^T + biases, fused cell
  ASeg a0{xb, 512, 8}, a1{rb, 1024, 16}, a2{h1b, 1024, 16};
  WSeg w0{W_ih1, 1536}, w1{W_ih1 + 512, 1536}, w2{W_hh1, 1024};
  lstm_gemm<<<256, 256, 0, stream>>>(a0, a1, a2, w0, w1, w2,
                                     b_ih1, b_hh1, c1, h1n, c1n, h1nb);

  // 3) LSTM2
  ASeg d0{h1nb, 1024, 16}, d1{h2b, 1024, 16}, d2{nullptr, 0, 0};
  WSeg v0{W_ih2, 1024}, v1{W_hh2, 1024}, v2{nullptr, 0};
  lstm_gemm<<<256, 256, 0, stream>>>(d0, d1, d2, v0, v1, v2,
                                     b_ih2, b_hh2, c2, h2n, c2n, h2nb);

  // 4) head projections (4 big + merged small heads)
  heads_gemm<<<260, 256, 0, stream>>>(h2nb, W_rk, W_wk, W_er, W_ad,
                                      b_rk, b_wk, b_er, b_ad,
                                      W_rb, b_rb, W_wb, b_wb, W_sh, b_sh, W_ga, b_ga,
                                      RK, WKb, ER, AD, Brb, Bwb, SHb, GAb);

  // 5) fused memory write + read
  ntm_rw<<<512, 256, 0, stream>>>(M_prev, WKb, ER, AD, RK, Bwb, Brb, SHb, GAb,
                                  M_o, wro, r_o);
}

// Round 8
// 457.313 us; speedup vs baseline: 1.1422x; 1.1422x over previous
//
#include <hip/hip_runtime.h>
#include <cstdint>
#include <cstddef>

// NTM cell: B=512, INP=512, C=1024, N=256, D=128, H=8
// d_out (floats): h1n(524288) c1n(524288) h2n(524288) c2n(524288)
//                 w_r(1048576) r(524288) M(16777216)

typedef __attribute__((ext_vector_type(4))) float f32x4;
typedef __attribute__((ext_vector_type(8))) __bf16 bf16x8;
typedef __attribute__((ext_vector_type(4))) unsigned short u16x4;
typedef __attribute__((ext_vector_type(8))) unsigned short u16x8;

struct ASeg { const unsigned short* A; int ldA; int kt; };
struct WSeg { const float* W; int ldW; };

__device__ __forceinline__ unsigned short f2bf(float f) {
  return __builtin_bit_cast(unsigned short, (__bf16)f);   // HW RNE convert
}
__device__ __forceinline__ float sigmoidf_(float x) { return 1.f / (1.f + expf(-x)); }
__device__ __forceinline__ float softplusf_(float x) {
  return fmaxf(x, 0.f) + log1pf(expf(-fabsf(x)));
}

// 512-tile grids: chunked XCD remap; 8 M-tiles sharing a B-panel per XCD.
__device__ __forceinline__ void xcd_decode512(int hid, int& k, int& g) {
  int xcd = hid & 7, slot = hid >> 3;  // slot 0..63
  g = xcd + 8 * (slot >> 3);           // 64 B-panel groups
  k = slot & 7;                        // 8 M-tiles per group
}

// ============ GEMM core: 64x64 tile, BK=64, 256 thr (4 waves of 16x64) ============
// A: bf16 global, staged via global_load_lds (16B) with inverse-swizzled SOURCE
// columns (linear LDS dest). B: fp32 weight rows, inline convert, swizzled ds_write.
// LDS: row r, logical elem e at phys r*64 + (e ^ ((r&7)<<3)).

__device__ __forceinline__ void stage_tile64(
    unsigned short* lAb, unsigned short* lBb,
    const float* (*s_brow)[64],
    const unsigned short* A0, int ldA0, const unsigned short* A1, int ldA1,
    const unsigned short* A2, int ldA2, int b0, int b1, int kt, int t)
{
  int si; const unsigned short* A; int ldA; int ktl;
  if (kt < b0)      { si = 0; ktl = kt;      A = A0; ldA = ldA0; }
  else if (kt < b1) { si = 1; ktl = kt - b0; A = A1; ldA = ldA1; }
  else              { si = 2; ktl = kt - b1; A = A2; ldA = ldA2; }
  const int kl = ktl * 64;
  const int wave = t >> 6, lane = t & 63;
  // ---- A: 2 issues/wave; each covers 8 rows x 64 bf16, linear LDS dest ----
  const int a_r8 = lane >> 3;
  const int a_col = (((lane & 7) ^ a_r8) * 8);         // inverse-swizzled src col
#pragma unroll
  for (int q = 0; q < 2; ++q) {
    const int R = (wave * 2 + q) * 8;
    const unsigned short* src = A + (size_t)(R + a_r8) * ldA + kl + a_col;
    __builtin_amdgcn_global_load_lds(
        (const __attribute__((address_space(1))) void*)src,
        (__attribute__((address_space(3))) void*)(lAb + R * 64), 16, 0, 0);
  }
  // ---- B: 64 rows fp32 -> bf16, swizzled ds_write ----
  const int brow0 = t >> 4, bseg = t & 15;
#pragma unroll
  for (int i = 0; i < 4; ++i) {
    const int row = brow0 + 16 * i;
    const float* wp = s_brow[si][row];
    f32x4 v = *(const f32x4*)(wp + kl + bseg * 4);
    u16x4 p; p.x = f2bf(v.x); p.y = f2bf(v.y); p.z = f2bf(v.z); p.w = f2bf(v.w);
    *(u16x4*)&lBb[row * 64 + ((bseg * 4) ^ ((row & 7) << 3))] = p;
  }
}

__device__ __forceinline__ void mfma_tile64(const unsigned short* lAb,
                                            const unsigned short* lBb,
                                            int t, f32x4 (&acc)[4])
{
  const int wave = t >> 6, lane = t & 63;
  const int lr = lane & 15, lk = lane >> 4;
#pragma unroll
  for (int kk = 0; kk < 2; ++kk) {
    const int ar = wave * 16 + lr;
    bf16x8 af = *(const bf16x8*)&lAb[ar * 64 + ((kk * 32 + lk * 8) ^ ((ar & 7) << 3))];
    bf16x8 bfr[4];
#pragma unroll
    for (int ni = 0; ni < 4; ++ni) {
      const int br = ni * 16 + lr;
      bfr[ni] = *(const bf16x8*)&lBb[br * 64 + ((kk * 32 + lk * 8) ^ ((br & 7) << 3))];
    }
#pragma unroll
    for (int ni = 0; ni < 4; ++ni)
      acc[ni] = __builtin_amdgcn_mfma_f32_16x16x32_bf16(af, bfr[ni], acc[ni], 0, 0, 0);
  }
}

// 2-phase: stage(next) -> mfma(cur) -> barrier. Multi-block/CU hides the drain.
#define GEMM_PIPELINE64(A0, LD0, A1, LD1, A2, LD2, B0, B1, KB, KE)                 \
  stage_tile64(lA[0], lB[0], s_brow, A0, LD0, A1, LD1, A2, LD2, B0, B1, KB, t);    \
  __syncthreads();                                                                 \
  _Pragma("unroll 1")                                                              \
  for (int kt = (KB); kt < (KE); ++kt) {                                           \
    const int cur = (kt - (KB)) & 1;                                               \
    if (kt + 1 < (KE))                                                             \
      stage_tile64(lA[cur ^ 1], lB[cur ^ 1], s_brow, A0, LD0, A1, LD1, A2, LD2,    \
                   B0, B1, kt + 1, t);                                             \
    mfma_tile64(lA[cur], lB[cur], t, acc);                                         \
    __syncthreads();                                                               \
  }

// ---------------- LSTM GEMM, split-K x2 -> partial gates (no bias) ----------------
__global__ __launch_bounds__(256, 4) void lstm_gemm(
    ASeg a0, ASeg a1, ASeg a2, WSeg w0, WSeg w1, WSeg w2,
    float* __restrict__ g0out, float* __restrict__ g1out, int khalf, int ktotal)
{
  __shared__ __align__(16) unsigned short lA[2][64 * 64];
  __shared__ __align__(16) unsigned short lB[2][64 * 64];
  __shared__ const float* s_brow[3][64];
  const int t = threadIdx.x;
  const int hid = blockIdx.x;
  const int split = hid >> 9;                    // grid = 1024
  int k, g; xcd_decode512(hid & 511, k, g);
  const int m0 = k * 64, n0 = g * 64;
  const int kb = split ? khalf : 0, ke = split ? ktotal : khalf;
  float* gout = split ? g1out : g0out;

  if (t < 192) {
    const int si = t >> 6, row = t & 63;
    const float* W = si == 0 ? w0.W : si == 1 ? w1.W : w2.W;
    const int ldW  = si == 0 ? w0.ldW : si == 1 ? w1.ldW : w2.ldW;
    if (W) s_brow[si][row] = W + (size_t)(n0 + row) * ldW;
  }
  __syncthreads();

  f32x4 acc[4];
#pragma unroll
  for (int j = 0; j < 4; ++j) acc[j] = (f32x4){0.f, 0.f, 0.f, 0.f};

  const unsigned short* A0 = a0.A + (size_t)m0 * a0.ldA;
  const unsigned short* A1 = a1.A + (size_t)m0 * a1.ldA;
  const unsigned short* A2 = a2.A ? a2.A + (size_t)m0 * a2.ldA : a0.A;
  const int b0 = a0.kt, b1 = b0 + a1.kt;
  GEMM_PIPELINE64(A0, a0.ldA, A1, a1.ldA, A2, a2.ldA, b0, b1, kb, ke)

  // C layout (m89-verified): col = lane&15 within frag, row = (lane>>4)*4 + reg
  const int lane = t & 63, wave = t >> 6;
  const int lr = lane & 15, lk = lane >> 4;
#pragma unroll
  for (int ni = 0; ni < 4; ++ni) {
    const int col = n0 + ni * 16 + lr;
#pragma unroll
    for (int jp = 0; jp < 4; ++jp) {
      const int r = m0 + wave * 16 + lk * 4 + jp;
      gout[(size_t)r * 4096 + col] = acc[ni][jp];
    }
  }
}

// ---------------- LSTM cell elementwise: g = g0+g1+biases; i,f,g,o ----------------
__global__ __launch_bounds__(256) void lstm_cell(
    const float* __restrict__ g0, const float* __restrict__ g1,
    const float* __restrict__ bih, const float* __restrict__ bhh,
    const float* __restrict__ cprev,
    float* __restrict__ hout, float* __restrict__ cout,
    unsigned short* __restrict__ hb)
{
  const int idx = blockIdx.x * 256 + threadIdx.x;   // f32x4 over 512*1024/4; grid 512
  const int b = idx >> 8, j4 = idx & 255;
  const int j = j4 * 4;
  const float* ga = g0 + (size_t)b * 4096;
  const float* gb = g1 + (size_t)b * 4096;
  f32x4 gi = *(const f32x4*)(ga + j)        + *(const f32x4*)(gb + j)
           + *(const f32x4*)(bih + j)        + *(const f32x4*)(bhh + j);
  f32x4 gf = *(const f32x4*)(ga + 1024 + j) + *(const f32x4*)(gb + 1024 + j)
           + *(const f32x4*)(bih + 1024 + j) + *(const f32x4*)(bhh + 1024 + j);
  f32x4 gc = *(const f32x4*)(ga + 2048 + j) + *(const f32x4*)(gb + 2048 + j)
           + *(const f32x4*)(bih + 2048 + j) + *(const f32x4*)(bhh + 2048 + j);
  f32x4 go = *(const f32x4*)(ga + 3072 + j) + *(const f32x4*)(gb + 3072 + j)
           + *(const f32x4*)(bih + 3072 + j) + *(const f32x4*)(bhh + 3072 + j);
  f32x4 c = *(const f32x4*)(cprev + (size_t)idx * 4);
  f32x4 cn, hn; u16x4 hp;
#pragma unroll
  for (int e = 0; e < 4; ++e) {
    float cne = sigmoidf_(gf[e]) * c[e] + sigmoidf_(gi[e]) * tanhf(gc[e]);
    float hne = sigmoidf_(go[e]) * tanhf(cne);
    cn[e] = cne; hn[e] = hne; hp[e] = f2bf(hne);
  }
  *(f32x4*)(cout + (size_t)idx * 4) = cn;
  *(f32x4*)(hout + (size_t)idx * 4) = hn;
  *(u16x4*)(hb + (size_t)idx * 4) = hp;
}

// ---------------- head projections: RK, WK, ER(sig), AD(tanh) + small heads -------
__global__ __launch_bounds__(256, 4) void heads_gemm(
    const unsigned short* __restrict__ A,
    const float* W0, const float* W1, const float* W2, const float* W3,
    const float* bb0, const float* bb1, const float* bb2, const float* bb3,
    const float* W_rb, const float* b_rb, const float* W_wb, const float* b_wb,
    const float* W_sh, const float* b_sh, const float* W_ga, const float* b_ga,
    float* o0, float* o1, float* o2, float* o3,
    float* Brw, float* Bww, float* SHw, float* GAw)
{
  __shared__ __align__(16) unsigned short lA[2][64 * 64];
  __shared__ __align__(16) unsigned short lB[2][64 * 64];
  __shared__ const float* s_brow[3][64];
  const int t = threadIdx.x;
  const int hid = blockIdx.x;
  const bool small = (hid >= 512);
  int m0, n0 = 0, z = 4;
  if (!small) {
    int k, g; xcd_decode512(hid, k, g);
    m0 = k * 64; n0 = (g & 15) * 64; z = g >> 4;
  } else {
    m0 = (hid - 512) * 64;
  }
  const float* W  = z == 0 ? W0 : z == 1 ? W1 : z == 2 ? W2 : z == 3 ? W3 : nullptr;
  const float* bb = z == 0 ? bb0 : z == 1 ? bb1 : z == 2 ? bb2 : bb3;
  float* o        = z == 0 ? o0 : z == 1 ? o1 : z == 2 ? o2 : o3;

  if (t < 64) {
    if (!small) {
      s_brow[0][t] = W + (size_t)(n0 + t) * 1024;
    } else {
      const float* p;
      if (t < 8)       p = W_rb + (size_t)t * 1024;
      else if (t < 16) p = W_wb + (size_t)(t - 8) * 1024;
      else if (t < 40) p = W_sh + (size_t)(t - 16) * 1024;
      else if (t < 48) p = W_ga + (size_t)(t - 40) * 1024;
      else             p = W_ga;            // dummy rows 48..63, outputs skipped
      s_brow[0][t] = p;
    }
  }
  __syncthreads();

  f32x4 acc[4];
#pragma unroll
  for (int j = 0; j < 4; ++j) acc[j] = (f32x4){0.f, 0.f, 0.f, 0.f};

  const unsigned short* A0 = A + (size_t)m0 * 1024;
  GEMM_PIPELINE64(A0, 1024, A0, 1024, A0, 1024, 16, 16, 0, 16)

  const int lane = t & 63, wave = t >> 6;
  const int lr = lane & 15, lk = lane >> 4;
  if (!small) {
#pragma unroll
    for (int ni = 0; ni < 4; ++ni) {
      const int col = n0 + ni * 16 + lr;
      const float bv = bb[col];
#pragma unroll
      for (int jp = 0; jp < 4; ++jp) {
        const int r = m0 + wave * 16 + lk * 4 + jp;
        float v = acc[ni][jp] + bv;
        if (z == 2) v = sigmoidf_(v);
        else if (z == 3) v = tanhf(v);
        o[(size_t)r * 1024 + col] = v;
      }
    }
  } else {
#pragma unroll
    for (int ni = 0; ni < 4; ++ni) {
      const int c = ni * 16 + lr;
#pragma unroll
      for (int jp = 0; jp < 4; ++jp) {
        const int r = m0 + wave * 16 + lk * 4 + jp;
        const float v = acc[ni][jp];
        if (c < 8)       Brw[r * 8 + c] = softplusf_(v + b_rb[c]);
        else if (c < 16) Bww[r * 8 + (c - 8)] = softplusf_(v + b_wb[c - 8]);
        else if (c < 40) SHw[(size_t)r * 24 + (c - 16)] = v + b_sh[c - 16];
        else if (c < 48) GAw[r * 8 + (c - 40)] = v + b_ga[c - 40];
      }
    }
  }
}

// ---------------- fp32 -> bf16 convert for GEMM A operands ----------------
__global__ __launch_bounds__(256) void cvt_bf16(
    const float* __restrict__ x, const float* __restrict__ rp,
    const float* __restrict__ h1, const float* __restrict__ h2,
    unsigned short* __restrict__ ob)
{
  const int i = blockIdx.x * 256 + threadIdx.x;       // 896 blocks
  const float* src; int off;
  if (i < 32768)       { src = x;  off = i; }
  else if (i < 98304)  { src = rp; off = i - 32768; }
  else if (i < 163840) { src = h1; off = i - 98304; }
  else                 { src = h2; off = i - 163840; }
  f32x4 a = *(const f32x4*)(src + (size_t)off * 8);
  f32x4 c = *(const f32x4*)(src + (size_t)off * 8 + 4);
  u16x8 p;
  p[0] = f2bf(a.x); p[1] = f2bf(a.y); p[2] = f2bf(a.z); p[3] = f2bf(a.w);
  p[4] = f2bf(c.x); p[5] = f2bf(c.y); p[6] = f2bf(c.z); p[7] = f2bf(c.w);
  *(u16x8*)(ob + (size_t)i * 8) = p;
}

// ---------------- fused memory write + read ----------------
// Batched-load cos pass: 2 memory rows per iteration (8 loads in flight).
__device__ __forceinline__ void cos_pass(const float* __restrict__ Mbase,
                                         const float (*s_k)[128],
                                         const float* s_scale, float (*s_w)[256],
                                         int b, int t)
{
  const int l8 = t & 7, rg = t >> 3;
  f32x4 kv0[8], kv1[8], kv2[8], kv3[8];
#pragma unroll
  for (int h = 0; h < 8; ++h) {
    kv0[h] = *(const f32x4*)&s_k[h][(l8 + 0) * 4];
    kv1[h] = *(const f32x4*)&s_k[h][(l8 + 8) * 4];
    kv2[h] = *(const f32x4*)&s_k[h][(l8 + 16) * 4];
    kv3[h] = *(const f32x4*)&s_k[h][(l8 + 24) * 4];
  }
#pragma unroll 1
  for (int jo = 0; jo < 4; ++jo) {
    const int na = jo * 64 + rg, nb = na + 32;
    const float* mra = Mbase + ((size_t)b * 256 + na) * 128;
    const float* mrb = Mbase + ((size_t)b * 256 + nb) * 128;
    f32x4 a0 = *(const f32x4*)(mra + (l8 + 0) * 4);
    f32x4 a1 = *(const f32x4*)(mra + (l8 + 8) * 4);
    f32x4 a2 = *(const f32x4*)(mra + (l8 + 16) * 4);
    f32x4 a3 = *(const f32x4*)(mra + (l8 + 24) * 4);
    f32x4 c0 = *(const f32x4*)(mrb + (l8 + 0) * 4);
    f32x4 c1 = *(const f32x4*)(mrb + (l8 + 8) * 4);
    f32x4 c2 = *(const f32x4*)(mrb + (l8 + 16) * 4);
    f32x4 c3 = *(const f32x4*)(mrb + (l8 + 24) * 4);
    f32x4 sa = a0 * a0 + a1 * a1 + a2 * a2 + a3 * a3;
    f32x4 sb = c0 * c0 + c1 * c1 + c2 * c2 + c3 * c3;
    float sqa = sa.x + sa.y + sa.z + sa.w;
    float sqb = sb.x + sb.y + sb.z + sb.w;
    float dota[8], dotb[8];
#pragma unroll
    for (int h = 0; h < 8; ++h) {
      f32x4 da = a0 * kv0[h] + a1 * kv1[h] + a2 * kv2[h] + a3 * kv3[h];
      f32x4 db = c0 * kv0[h] + c1 * kv1[h] + c2 * kv2[h] + c3 * kv3[h];
      dota[h] = da.x + da.y + da.z + da.w;
      dotb[h] = db.x + db.y + db.z + db.w;
    }
#pragma unroll
    for (int mk = 1; mk < 8; mk <<= 1) {
      sqa += __shfl_xor(sqa, mk, 64);
      sqb += __shfl_xor(sqb, mk, 64);
#pragma unroll
      for (int h = 0; h < 8; ++h) {
        dota[h] += __shfl_xor(dota[h], mk, 64);
        dotb[h] += __shfl_xor(dotb[h], mk, 64);
      }
    }
    if (l8 == 0) {
      const float ia = 1.f / fmaxf(sqrtf(sqa), 1e-12f);
      const float ib = 1.f / fmaxf(sqrtf(sqb), 1e-12f);
#pragma unroll
      for (int h = 0; h < 8; ++h) {
        s_w[h][na] = dota[h] * ia * s_scale[h];
        s_w[h][nb] = dotb[h] * ib * s_scale[h];
      }
    }
  }
}

__device__ __forceinline__ void softmax256(float (*s_w)[256], int t) {
  const int h = t >> 5, l32 = t & 31;
  float v[8]; float mx = -3.4e38f;
#pragma unroll
  for (int i = 0; i < 8; ++i) { v[i] = s_w[h][l32 + 32 * i]; mx = fmaxf(mx, v[i]); }
#pragma unroll
  for (int mk = 1; mk < 32; mk <<= 1) mx = fmaxf(mx, __shfl_xor(mx, mk, 64));
  float sum = 0.f;
#pragma unroll
  for (int i = 0; i < 8; ++i) { v[i] = expf(v[i] - mx); sum += v[i]; }
#pragma unroll
  for (int mk = 1; mk < 32; mk <<= 1) sum += __shfl_xor(sum, mk, 64);
  const float inv = 1.f / sum;
#pragma unroll
  for (int i = 0; i < 8; ++i) s_w[h][l32 + 32 * i] = v[i] * inv;
}

__global__ __launch_bounds__(256, 2) void ntm_rw(
    const float* __restrict__ Mp, const float* __restrict__ WK,
    const float* __restrict__ ER, const float* __restrict__ AD,
    const float* __restrict__ RK,
    const float* __restrict__ Bw, const float* __restrict__ Br,
    const float* __restrict__ SH, const float* __restrict__ GA,
    float* __restrict__ Mo, float* __restrict__ wr_o, float* __restrict__ r_o)
{
  const int b = blockIdx.x, t = threadIdx.x;
  __shared__ __align__(16) float s_wk[8][128], s_er[8][128], s_ad[8][128], s_rk[8][128];
  __shared__ __align__(16) float s_w[8][256], s_w2[8][256];
  __shared__ __align__(16) float s_part[8][8][128];
  __shared__ float s_scw[8], s_scr[8], s_sh3[8][3], s_g[8];

  {
    const int h = t >> 5, d16 = (t & 31) * 4;
    const size_t off = (size_t)b * 1024 + t * 4;
    *(f32x4*)&s_wk[h][d16] = *(const f32x4*)(WK + off);
    *(f32x4*)&s_er[h][d16] = *(const f32x4*)(ER + off);
    *(f32x4*)&s_ad[h][d16] = *(const f32x4*)(AD + off);
    *(f32x4*)&s_rk[h][d16] = *(const f32x4*)(RK + off);
  }
  __syncthreads();
  if (t < 64) {
    const int h = t >> 3, l8 = t & 7;
    f32x4 aw = {0,0,0,0}, ar = {0,0,0,0};
#pragma unroll
    for (int q = 0; q < 4; ++q) {
      f32x4 w = *(const f32x4*)&s_wk[h][(l8 + q * 8) * 4];
      f32x4 r = *(const f32x4*)&s_rk[h][(l8 + q * 8) * 4];
      aw += w * w; ar += r * r;
    }
    float sw = aw.x + aw.y + aw.z + aw.w;
    float sr = ar.x + ar.y + ar.z + ar.w;
#pragma unroll
    for (int mk = 1; mk < 8; mk <<= 1) {
      sw += __shfl_xor(sw, mk, 64); sr += __shfl_xor(sr, mk, 64);
    }
    if (l8 == 0) {
      s_scw[h] = Bw[b * 8 + h] / fmaxf(sqrtf(sw), 1e-12f);
      s_scr[h] = Br[b * 8 + h] / fmaxf(sqrtf(sr), 1e-12f);
    }
  }
  if (t < 8) {
    s_g[t] = 1.f + softplusf_(GA[b * 8 + t]);
    float s0 = SH[b * 24 + t * 3], s1 = SH[b * 24 + t * 3 + 1], s2 = SH[b * 24 + t * 3 + 2];
    float mx = fmaxf(s0, fmaxf(s1, s2));
    float e0 = expf(s0 - mx), e1 = expf(s1 - mx), e2 = expf(s2 - mx);
    float inv = 1.f / (e0 + e1 + e2);
    s_sh3[t][0] = e0 * inv; s_sh3[t][1] = e1 * inv; s_sh3[t][2] = e2 * inv;
  }
  __syncthreads();

  // -------- write head: content weights on M_prev --------
  cos_pass(Mp, s_wk, s_scw, s_w, b, t);
  __syncthreads();
  softmax256(s_w, t);
  __syncthreads();

  // -------- M = Mp*(1 - sum_h w e) + sum_h w a : 4-batched loads --------
  {
    const int d16 = (t & 31) * 4;
    f32x4 er8[8], ad8[8];
#pragma unroll
    for (int h = 0; h < 8; ++h) {
      er8[h] = *(const f32x4*)&s_er[h][d16];
      ad8[h] = *(const f32x4*)&s_ad[h][d16];
    }
#pragma unroll 1
    for (int jo = 0; jo < 8; ++jo) {
      const int idx0 = jo * 1024 + t;
      f32x4 m0v = *(const f32x4*)(Mp + (size_t)b * 32768 + (size_t)(idx0 + 0) * 4);
      f32x4 m1v = *(const f32x4*)(Mp + (size_t)b * 32768 + (size_t)(idx0 + 256) * 4);
      f32x4 m2v = *(const f32x4*)(Mp + (size_t)b * 32768 + (size_t)(idx0 + 512) * 4);
      f32x4 m3v = *(const f32x4*)(Mp + (size_t)b * 32768 + (size_t)(idx0 + 768) * 4);
      f32x4 mv[4] = {m0v, m1v, m2v, m3v};
#pragma unroll
      for (int i = 0; i < 4; ++i) {
        const int idx = idx0 + i * 256;
        const int n = idx >> 5;
        f32x4 er = {0,0,0,0}, ad = {0,0,0,0};
#pragma unroll
        for (int h = 0; h < 8; ++h) {
          const float w = s_w[h][n];
          er += w * er8[h];
          ad += w * ad8[h];
        }
        f32x4 o;
#pragma unroll
        for (int e = 0; e < 4; ++e) o[e] = mv[i][e] * (1.f - er[e]) + ad[e];
        *(f32x4*)(Mo + (size_t)b * 32768 + (size_t)idx * 4) = o;
      }
    }
  }
  __syncthreads();

  // -------- read head: content on new M --------
  cos_pass(Mo, s_rk, s_scr, s_w, b, t);
  __syncthreads();
  softmax256(s_w, t);
  __syncthreads();

  // -------- shift + sharpen --------
  {
    const int h = t >> 5, l32 = t & 31;
    float vals[8]; float sum = 0.f;
#pragma unroll
    for (int i = 0; i < 8; ++i) {
      const int n = l32 + 32 * i;
      float ws = s_w[h][(n + 1) & 255] * s_sh3[h][0]
               + s_w[h][n] * s_sh3[h][1]
               + s_w[h][(n - 1) & 255] * s_sh3[h][2];
      float wg = powf(ws, s_g[h]);
      vals[i] = wg; sum += wg;
    }
#pragma unroll
    for (int mk = 1; mk < 32; mk <<= 1) sum += __shfl_xor(sum, mk, 64);
    const float inv = 1.f / (sum + 1e-12f);
#pragma unroll
    for (int i = 0; i < 8; ++i) {
      const int n = l32 + 32 * i;
      const float w = vals[i] * inv;
      s_w2[h][n] = w;
      wr_o[((size_t)b * 8 + h) * 256 + n] = w;
    }
  }
  __syncthreads();

  // -------- r = w_r @ M : 4-batched loads, n-parallel partials, LDS reduce --------
  {
    const int gq = t >> 5, q = t & 31;
    f32x4 pr[8];
#pragma unroll
    for (int h = 0; h < 8; ++h) pr[h] = (f32x4){0,0,0,0};
#pragma unroll 1
    for (int jo = 0; jo < 8; ++jo) {
      const int nb0 = jo * 32 + gq;              // n = nb0 + i*8
      f32x4 v0 = *(const f32x4*)(Mo + (size_t)b * 32768 + (size_t)(nb0 + 0)  * 128 + q * 4);
      f32x4 v1 = *(const f32x4*)(Mo + (size_t)b * 32768 + (size_t)(nb0 + 8)  * 128 + q * 4);
      f32x4 v2 = *(const f32x4*)(Mo + (size_t)b * 32768 + (size_t)(nb0 + 16) * 128 + q * 4);
      f32x4 v3 = *(const f32x4*)(Mo + (size_t)b * 32768 + (size_t)(nb0 + 24) * 128 + q * 4);
      f32x4 vv[4] = {v0, v1, v2, v3};
#pragma unroll
      for (int i = 0; i < 4; ++i) {
        const int n = nb0 + i * 8;
#pragma unroll
        for (int h = 0; h < 8; ++h) pr[h] += s_w2[h][n] * vv[i];
      }
    }
#pragma unroll
    for (int h = 0; h < 8; ++h) *(f32x4*)&s_part[gq][h][q * 4] = pr[h];
  }
  __syncthreads();
  {
    const int h = t >> 5, q = t & 31;
    f32x4 a = (f32x4){0,0,0,0};
#pragma unroll
    for (int g2 = 0; g2 < 8; ++g2) a += *(const f32x4*)&s_part[g2][h][q * 4];
    *(f32x4*)(r_o + ((size_t)b * 8 + h) * 128 + q * 4) = a;
  }
}

// ---------------- launch ----------------
extern "C" void kernel_launch(void* const* d_in, const int* in_sizes, int n_in,
                              void* d_out, int out_size, void* d_ws, size_t ws_size,
                              hipStream_t stream)
{
  const float* x      = (const float*)d_in[0];
  const float* h1     = (const float*)d_in[1];
  const float* c1     = (const float*)d_in[2];
  const float* h2     = (const float*)d_in[3];
  const float* c2     = (const float*)d_in[4];
  const float* r_prev = (const float*)d_in[6];
  const float* M_prev = (const float*)d_in[7];
  const float* W_ih1  = (const float*)d_in[8];
  const float* W_hh1  = (const float*)d_in[9];
  const float* b_ih1  = (const float*)d_in[10];
  const float* b_hh1  = (const float*)d_in[11];
  const float* W_ih2  = (const float*)d_in[12];
  const float* W_hh2  = (const float*)d_in[13];
  const float* b_ih2  = (const float*)d_in[14];
  const float* b_hh2  = (const float*)d_in[15];
  const float* W_rk   = (const float*)d_in[16];
  const float* b_rk   = (const float*)d_in[17];
  const float* W_wk   = (const float*)d_in[18];
  const float* b_wk   = (const float*)d_in[19];
  const float* W_rb   = (const float*)d_in[20];
  const float* b_rb   = (const float*)d_in[21];
  const float* W_wb   = (const float*)d_in[22];
  const float* b_wb   = (const float*)d_in[23];
  const float* W_er   = (const float*)d_in[24];
  const float* b_er   = (const float*)d_in[25];
  const float* W_ad   = (const float*)d_in[26];
  const float* b_ad   = (const float*)d_in[27];
  const float* W_sh   = (const float*)d_in[28];
  const float* b_sh   = (const float*)d_in[29];
  const float* W_ga   = (const float*)d_in[30];
  const float* b_ga   = (const float*)d_in[31];

  float* out = (float*)d_out;
  float* h1n = out;
  float* c1n = out + 524288;
  float* h2n = out + 1048576;
  float* c2n = out + 1572864;
  float* wro = out + 2097152;
  float* r_o = out + 3145728;
  float* M_o = out + 3670016;

  // ws: RK/WK/ER/AD + smalls (live through ntm_rw) always in ws.
  // gates g0/g1 (16.8 MB) + bf16 A buffers (5.77 MB) fall back to M_o region
  // (dead until ntm_rw) when ws is too small.
  float* wsf = (float*)d_ws;
  float* RK  = wsf;                     // 524288 floats each
  float* WKb = RK + 524288;
  float* ER  = WKb + 524288;
  float* AD  = ER + 524288;
  float* Brb = AD + 524288;             // 4096
  float* Bwb = Brb + 4096;
  float* SHb = Bwb + 4096;              // 12288
  float* GAb = SHb + 12288;             // 4096
  const size_t head_f32   = 2121728;                    // floats
  const size_t gates_f32  = 2 * 2097152;                // floats
  const size_t bf16_elems = 2883584;                    // shorts
  float* g0; float* g1; unsigned short* bfb;
  if (ws_size >= (head_f32 + gates_f32) * 4 + bf16_elems * 2) {
    g0 = wsf + head_f32;
    g1 = g0 + 2097152;
    bfb = (unsigned short*)(g1 + 2097152);
  } else {
    g0 = M_o;                                           // M_o head: dead until ntm_rw
    g1 = M_o + 2097152;
    bfb = (unsigned short*)(M_o + (16777216 - (bf16_elems + 1) / 2));  // M_o tail
  }
  unsigned short* xb   = bfb;           // 262144
  unsigned short* rb   = xb + 262144;   // 524288 each
  unsigned short* h1b  = rb + 524288;
  unsigned short* h2b  = h1b + 524288;
  unsigned short* h1nb = h2b + 524288;
  unsigned short* h2nb = h1nb + 524288;

  // 1) fp32 -> bf16 for GEMM A operands
  cvt_bf16<<<896, 256, 0, stream>>>(x, r_prev, h1, h2, xb);

  // 2) LSTM1 GEMM (split-K2) + cell
  ASeg a0{xb, 512, 8}, a1{rb, 1024, 16}, a2{h1b, 1024, 16};
  WSeg w0{W_ih1, 1536}, w1{W_ih1 + 512, 1536}, w2{W_hh1, 1024};
  lstm_gemm<<<1024, 256, 0, stream>>>(a0, a1, a2, w0, w1, w2, g0, g1, 20, 40);
  lstm_cell<<<512, 256, 0, stream>>>(g0, g1, b_ih1, b_hh1, c1, h1n, c1n, h1nb);

  // 3) LSTM2 GEMM (split-K2) + cell
  ASeg d0{h1nb, 1024, 16}, d1{h2b, 1024, 16}, d2{nullptr, 0, 0};
  WSeg v0{W_ih2, 1024}, v1{W_hh2, 1024}, v2{nullptr, 0};
  lstm_gemm<<<1024, 256, 0, stream>>>(d0, d1, d2, v0, v1, v2, g0, g1, 16, 32);
  lstm_cell<<<512, 256, 0, stream>>>(g0, g1, b_ih2, b_hh2, c2, h2n, c2n, h2nb);

  // 4) head projections (4 big + 8 small-head blocks)
  heads_gemm<<<520, 256, 0, stream>>>(h2nb, W_rk, W_wk, W_er, W_ad,
                                      b_rk, b_wk, b_er, b_ad,
                                      W_rb, b_rb, W_wb, b_wb, W_sh, b_sh, W_ga, b_ga,
                                      RK, WKb, ER, AD, Brb, Bwb, SHb, GAb);

  // 5) fused memory write + read
  ntm_rw<<<512, 256, 0, stream>>>(M_prev, WKb, ER, AD, RK, Bwb, Brb, SHb, GAb,
                                  M_o, wro, r_o);
}